// Round 1
// baseline (275.557 us; speedup 1.0000x reference)
//
#include <hip/hip_runtime.h>
#include <math.h>

// Problem constants
constexpr int F   = 1433;          // FEAT
constexpr int NB  = 64;            // batch
constexpr int KN  = 8;             // neighbors
constexpr int BF  = NB * F;        // 91712
constexpr int FF  = F * F;         // 2053489
constexpr float EPS = 1e-5f;

// Workspace layout (float offsets), all 256-float aligned
constexpr int O_YS = 0;            // [BF]   ys[b,g] = sum_k neighbor
constexpr int O_D  = 92160;        // [BF]   column sums D[b,g]
constexpr int O_W  = 184320;       // [BF]   w = xs/D (guarded)
constexpr int O_Q  = 276480;       // [BF]   q = 1/D (guarded)
constexpr int O_Y1 = 368640;       // [BF]   y1 = xs + s1
constexpr int O_H  = 460800;       // [2*BF] h1n, layout [m=b*2+c][f]
constexpr int O_Y2 = 645120;       // [2*BF] y2 accumulator
constexpr int O_A  = 829440;       // [FF]   A = sum_b norm (+adj_buf)
constexpr int O_ST = 2887680;      // [32]   stats/consts

// ---------------- K1: ys[b,g] = sum_k neighbor[b,k,g] ----------------
__global__ __launch_bounds__(256) void k_ys(const float* __restrict__ nb,
                                            float* __restrict__ ys) {
  int i = blockIdx.x * 256 + threadIdx.x;
  if (i >= BF) return;
  int b = i / F, g = i - b * F;
  const float* p = nb + (size_t)b * KN * F + g;
  float s = 0.f;
#pragma unroll
  for (int k = 0; k < KN; ++k) s += p[k * F];
  ys[i] = s;
}

// ---------------- K2: D[b,g] = sum_f sqrt(ys[b,g]*xs[b,f] + xs[b,g]*ys[b,f])
// one wave per (b,g); block stages xs,ys rows in LDS; 16 g per block
__global__ __launch_bounds__(256) void k_D(const float* __restrict__ xs,
                                           const float* __restrict__ ys,
                                           float* __restrict__ D) {
  __shared__ float xl[F], yl[F];
  const int b = blockIdx.x;
  for (int i = threadIdx.x; i < F; i += 256) {
    xl[i] = xs[b * F + i];
    yl[i] = ys[b * F + i];
  }
  __syncthreads();
  const int wave = threadIdx.x >> 6, lane = threadIdx.x & 63;
#pragma unroll
  for (int sub = 0; sub < 4; ++sub) {
    int g = blockIdx.y * 16 + wave * 4 + sub;
    if (g >= F) break;
    float a = yl[g], c = xl[g];
    float acc = 0.f;
    for (int f = lane; f < F; f += 64)
      acc += __builtin_amdgcn_sqrtf(fmaf(a, xl[f], c * yl[f]));
#pragma unroll
    for (int o = 32; o; o >>= 1) acc += __shfl_down(acc, o, 64);
    if (lane == 0) D[b * F + g] = acc;
  }
}

// ---------------- K2b: w = xs/D, q = 1/D (0 when D==0) ----------------
__global__ __launch_bounds__(256) void k_wq(const float* __restrict__ xs,
                                            const float* __restrict__ D,
                                            float* __restrict__ w,
                                            float* __restrict__ q) {
  int i = blockIdx.x * 256 + threadIdx.x;
  if (i >= BF) return;
  float d = D[i];
  float inv = (d > 0.f) ? 1.f / d : 0.f;
  q[i] = inv;
  w[i] = xs[i] * inv;
}

// ---------------- K3: y1[b,f] = xs[b,f] + sum_g sqrt(xs[b,f]ys[b,g]+ys[b,f]xs[b,g]) * w[b,g]
__global__ __launch_bounds__(256) void k_y1(const float* __restrict__ xs,
                                            const float* __restrict__ ys,
                                            const float* __restrict__ w,
                                            float* __restrict__ y1) {
  __shared__ float xl[F], yl[F], wl[F];
  const int b = blockIdx.x;
  for (int i = threadIdx.x; i < F; i += 256) {
    xl[i] = xs[b * F + i];
    yl[i] = ys[b * F + i];
    wl[i] = w[b * F + i];
  }
  __syncthreads();
  const int wave = threadIdx.x >> 6, lane = threadIdx.x & 63;
#pragma unroll
  for (int sub = 0; sub < 4; ++sub) {
    int f = blockIdx.y * 16 + wave * 4 + sub;
    if (f >= F) break;
    float a = xl[f], c = yl[f];
    float acc = 0.f;
    for (int g = lane; g < F; g += 64)
      acc += __builtin_amdgcn_sqrtf(fmaf(a, yl[g], c * xl[g])) * wl[g];
#pragma unroll
    for (int o = 32; o; o >>= 1) acc += __shfl_down(acc, o, 64);
    if (lane == 0) y1[b * F + f] = a + acc;
  }
}

// ---------------- K4: A[f,g] = adj_buf[f,g] + sum_b sqrt(t)*q[b,g] ----------------
// thread per g, 8 f rows per thread; f-side scalars staged in LDS
__global__ __launch_bounds__(256) void k_A(const float* __restrict__ xs,
                                           const float* __restrict__ ys,
                                           const float* __restrict__ q,
                                           const float* __restrict__ adjb,
                                           float* __restrict__ Aout) {
  __shared__ float fxl[NB][8], fyl[NB][8];
  const int fbase = blockIdx.y * 8;
  for (int i = threadIdx.x; i < NB * 8; i += 256) {
    int b = i >> 3, j = i & 7;
    int f = fbase + j;
    float vx = 0.f, vy = 0.f;
    if (f < F) { vx = xs[b * F + f]; vy = ys[b * F + f]; }
    fxl[b][j] = vx;
    fyl[b][j] = vy;
  }
  __syncthreads();
  const int g = blockIdx.x * 256 + threadIdx.x;
  if (g >= F) return;
  float acc[8] = {};
  for (int b = 0; b < NB; ++b) {
    float gx = xs[b * F + g], gy = ys[b * F + g], gq = q[b * F + g];
#pragma unroll
    for (int j = 0; j < 8; ++j) {
      float t = fmaf(fxl[b][j], gy, gx * fyl[b][j]);
      acc[j] = fmaf(__builtin_amdgcn_sqrtf(t), gq, acc[j]);
    }
  }
#pragma unroll
  for (int j = 0; j < 8; ++j) {
    int f = fbase + j;
    if (f < F) Aout[f * F + g] = acc[j] + adjb[f * F + g];
  }
}

// ---------------- K5: sum / sumsq of y1 ----------------
__global__ __launch_bounds__(256) void k_stats1(const float* __restrict__ y1,
                                                float* __restrict__ stats) {
  float s = 0.f, sq = 0.f;
  for (int i = blockIdx.x * 256 + threadIdx.x; i < BF; i += gridDim.x * 256) {
    float v = y1[i];
    s += v;
    sq += v * v;
  }
#pragma unroll
  for (int o = 32; o; o >>= 1) {
    s += __shfl_down(s, o, 64);
    sq += __shfl_down(sq, o, 64);
  }
  __shared__ float ls[4], lq[4];
  int wave = threadIdx.x >> 6, lane = threadIdx.x & 63;
  if (lane == 0) { ls[wave] = s; lq[wave] = sq; }
  __syncthreads();
  if (threadIdx.x == 0) {
    atomicAdd(&stats[0], ls[0] + ls[1] + ls[2] + ls[3]);
    atomicAdd(&stats[1], lq[0] + lq[1] + lq[2] + lq[3]);
  }
}

// ---------------- K5b: BN1 constants (b1 cancels inside BN) ----------------
__global__ void k_bn1c(const float* __restrict__ W1, const float* __restrict__ g1,
                       const float* __restrict__ be1, float* __restrict__ stats) {
  float mu = stats[0] / (float)BF;
  float var = stats[1] / (float)BF - mu * mu;
  for (int c = 0; c < 2; ++c) {
    float w = W1[c];  // W1 shape (2,1)
    float kc = w * g1[c] / sqrtf(w * w * var + EPS);
    stats[8 + c] = kc;
    stats[10 + c] = -kc * mu + be1[c];
  }
}

// ---------------- K6: H[m,f] = softsign(k_c*y1 + c_c); y2 init = 64*H ----------------
__global__ __launch_bounds__(256) void k_h1(const float* __restrict__ y1,
                                            const float* __restrict__ stats,
                                            float* __restrict__ Hm,
                                            float* __restrict__ y2) {
  int i = blockIdx.x * 256 + threadIdx.x;
  if (i >= BF) return;
  int b = i / F, f = i - b * F;
  float v = y1[i];
#pragma unroll
  for (int c = 0; c < 2; ++c) {
    float h = fmaf(stats[8 + c], v, stats[10 + c]);
    h = h / (1.f + fabsf(h));
    int idx = (b * 2 + c) * F + f;
    Hm[idx] = h;
    y2[idx] = 64.f * h;
  }
}

// ---------------- K7: y2[m,f] += sum_g A[f,g]*H[m,g]  (split-K, LDS-tiled) ----------------
constexpr int GEMM_SPLIT = 12;
constexpr int GEMM_KCH = 120;  // ceil(1433/12)
__global__ __launch_bounds__(256) void k_gemm(const float* __restrict__ A,
                                              const float* __restrict__ H,
                                              float* __restrict__ y2) {
  __shared__ __align__(16) float Al[32 * 36];   // [gi][ff], stride 36
  __shared__ __align__(16) float Hl[32 * 132];  // [gi][mm], stride 132
  const int f0 = blockIdx.x * 32;
  const int gs = blockIdx.y * GEMM_KCH;
  const int ge = min(gs + GEMM_KCH, F);
  const int tid = threadIdx.x;
  const int fsub = (tid & 7) * 4;
  const int msub = (tid >> 3) * 4;
  float acc[4][4] = {};
  for (int gc = gs; gc < ge; gc += 32) {
    {
      int l = tid;
#pragma unroll
      for (int r = 0; r < 4; ++r, l += 256) {
        int ff = l >> 5, gi = l & 31;
        int f = f0 + ff, g = gc + gi;
        Al[gi * 36 + ff] = (f < F && g < ge) ? A[f * F + g] : 0.f;
      }
    }
    {
      int l = tid;
#pragma unroll
      for (int r = 0; r < 16; ++r, l += 256) {
        int mm = l >> 5, gi = l & 31;
        int g = gc + gi;
        Hl[gi * 132 + mm] = (g < ge) ? H[mm * F + g] : 0.f;
      }
    }
    __syncthreads();
#pragma unroll 4
    for (int gi = 0; gi < 32; ++gi) {
      float4 a4 = *(const float4*)&Al[gi * 36 + fsub];
      float4 h4 = *(const float4*)&Hl[gi * 132 + msub];
      float av[4] = {a4.x, a4.y, a4.z, a4.w};
      float hv[4] = {h4.x, h4.y, h4.z, h4.w};
#pragma unroll
      for (int i = 0; i < 4; ++i)
#pragma unroll
        for (int j = 0; j < 4; ++j)
          acc[i][j] = fmaf(av[i], hv[j], acc[i][j]);
    }
    __syncthreads();
  }
#pragma unroll
  for (int i = 0; i < 4; ++i) {
    int f = f0 + fsub + i;
    if (f < F) {
#pragma unroll
      for (int j = 0; j < 4; ++j) {
        int m = msub + j;
        atomicAdd(&y2[m * F + f], acc[i][j]);
      }
    }
  }
}

// ---------------- K8: 5 moments of (u,v) over (b,f) ----------------
__global__ __launch_bounds__(256) void k_stats2(const float* __restrict__ y2,
                                                float* __restrict__ stats) {
  float su = 0.f, sv = 0.f, suu = 0.f, svv = 0.f, suv = 0.f;
  for (int i = blockIdx.x * 256 + threadIdx.x; i < BF; i += gridDim.x * 256) {
    int b = i / F, f = i - b * F;
    float u = y2[(2 * b) * F + f];
    float v = y2[(2 * b + 1) * F + f];
    su += u; sv += v; suu += u * u; svv += v * v; suv += u * v;
  }
#pragma unroll
  for (int o = 32; o; o >>= 1) {
    su += __shfl_down(su, o, 64);
    sv += __shfl_down(sv, o, 64);
    suu += __shfl_down(suu, o, 64);
    svv += __shfl_down(svv, o, 64);
    suv += __shfl_down(suv, o, 64);
  }
  __shared__ float red[5][4];
  int wave = threadIdx.x >> 6, lane = threadIdx.x & 63;
  if (lane == 0) {
    red[0][wave] = su; red[1][wave] = sv; red[2][wave] = suu;
    red[3][wave] = svv; red[4][wave] = suv;
  }
  __syncthreads();
  if (threadIdx.x == 0) {
    atomicAdd(&stats[2], red[0][0] + red[0][1] + red[0][2] + red[0][3]);
    atomicAdd(&stats[3], red[1][0] + red[1][1] + red[1][2] + red[1][3]);
    atomicAdd(&stats[4], red[2][0] + red[2][1] + red[2][2] + red[2][3]);
    atomicAdd(&stats[5], red[3][0] + red[3][1] + red[3][2] + red[3][3]);
    atomicAdd(&stats[6], red[4][0] + red[4][1] + red[4][2] + red[4][3]);
  }
}

// ---------------- K8b: BN2 constants -> h2n = softsign(A_o*u + B_o*v + C_o) ----------------
__global__ void k_bn2c(const float* __restrict__ W2, const float* __restrict__ b2,
                       const float* __restrict__ g2, const float* __restrict__ be2,
                       float* __restrict__ stats) {
  float n = (float)BF;
  float Eu = stats[2] / n, Ev = stats[3] / n;
  float Euu = stats[4] / n, Evv = stats[5] / n, Euv = stats[6] / n;
  for (int o = 0; o < 2; ++o) {
    float w0 = W2[o * 2 + 0], w1 = W2[o * 2 + 1];
    float mean = w0 * Eu + w1 * Ev + b2[o];
    float Eh2 = w0 * w0 * Euu + 2.f * w0 * w1 * Euv + w1 * w1 * Evv +
                2.f * b2[o] * (w0 * Eu + w1 * Ev) + b2[o] * b2[o];
    float var = Eh2 - mean * mean;
    float inv = g2[o] / sqrtf(var + EPS);
    stats[16 + o * 3 + 0] = w0 * inv;
    stats[16 + o * 3 + 1] = w1 * inv;
    stats[16 + o * 3 + 2] = (b2[o] - mean) * inv + be2[o];
  }
}

// ---------------- K9: out[b,o] = sum_f Wc[o,f]*h2n0 + Wc[o,F+f]*h2n1 + bc[o] ----------------
__global__ __launch_bounds__(256) void k_out(const float* __restrict__ y2,
                                             const float* __restrict__ stats,
                                             const float* __restrict__ Wc,
                                             const float* __restrict__ bc,
                                             float* __restrict__ out) {
  const int b = blockIdx.x;
  float A0 = stats[16], B0 = stats[17], C0 = stats[18];
  float A1 = stats[19], B1 = stats[20], C1 = stats[21];
  float acc[7] = {};
  for (int f = threadIdx.x; f < F; f += 256) {
    float u = y2[(2 * b) * F + f], v = y2[(2 * b + 1) * F + f];
    float h0 = fmaf(A0, u, fmaf(B0, v, C0));
    h0 = h0 / (1.f + fabsf(h0));
    float h1 = fmaf(A1, u, fmaf(B1, v, C1));
    h1 = h1 / (1.f + fabsf(h1));
#pragma unroll
    for (int o = 0; o < 7; ++o) acc[o] = fmaf(Wc[o * (2 * F) + f], h0, acc[o]);
#pragma unroll
    for (int o = 0; o < 7; ++o) acc[o] = fmaf(Wc[o * (2 * F) + F + f], h1, acc[o]);
  }
#pragma unroll
  for (int o = 0; o < 7; ++o) {
#pragma unroll
    for (int s = 32; s; s >>= 1) acc[o] += __shfl_down(acc[o], s, 64);
  }
  __shared__ float red[7][4];
  int wave = threadIdx.x >> 6, lane = threadIdx.x & 63;
  if (lane == 0) {
#pragma unroll
    for (int o = 0; o < 7; ++o) red[o][wave] = acc[o];
  }
  __syncthreads();
  if (threadIdx.x < 7) {
    int o = threadIdx.x;
    out[b * 7 + o] = red[o][0] + red[o][1] + red[o][2] + red[o][3] + bc[o];
  }
}

extern "C" void kernel_launch(void* const* d_in, const int* in_sizes, int n_in,
                              void* d_out, int out_size, void* d_ws, size_t ws_size,
                              hipStream_t stream) {
  const float* x    = (const float*)d_in[0];   // [64,1,1433] -> xs
  const float* nb   = (const float*)d_in[1];   // [64,8,1433]
  const float* adjb = (const float*)d_in[2];   // [1,1433,1433] zeros
  const float* W1   = (const float*)d_in[3];   // [2,1]
  const float* W2   = (const float*)d_in[5];   // [2,2]
  const float* b2   = (const float*)d_in[6];   // [2]
  const float* g1   = (const float*)d_in[7];
  const float* be1  = (const float*)d_in[8];
  const float* g2   = (const float*)d_in[9];
  const float* be2  = (const float*)d_in[10];
  const float* Wc   = (const float*)d_in[11];  // [7, 2866]
  const float* bc   = (const float*)d_in[12];  // [7]
  float* out = (float*)d_out;
  float* ws = (float*)d_ws;

  float* ys = ws + O_YS;
  float* D  = ws + O_D;
  float* w  = ws + O_W;
  float* q  = ws + O_Q;
  float* y1 = ws + O_Y1;
  float* Hm = ws + O_H;
  float* y2 = ws + O_Y2;
  float* A  = ws + O_A;
  float* st = ws + O_ST;

  hipMemsetAsync(st, 0, 32 * sizeof(float), stream);

  k_ys<<<(BF + 255) / 256, 256, 0, stream>>>(nb, ys);
  k_D<<<dim3(NB, (F + 15) / 16), 256, 0, stream>>>(x, ys, D);
  k_wq<<<(BF + 255) / 256, 256, 0, stream>>>(x, D, w, q);
  k_y1<<<dim3(NB, (F + 15) / 16), 256, 0, stream>>>(x, ys, w, y1);
  k_A<<<dim3((F + 255) / 256, (F + 7) / 8), 256, 0, stream>>>(x, ys, q, adjb, A);
  k_stats1<<<128, 256, 0, stream>>>(y1, st);
  k_bn1c<<<1, 1, 0, stream>>>(W1, g1, be1, st);
  k_h1<<<(BF + 255) / 256, 256, 0, stream>>>(y1, st, Hm, y2);
  k_gemm<<<dim3((F + 31) / 32, GEMM_SPLIT), 256, 0, stream>>>(A, Hm, y2);
  k_stats2<<<128, 256, 0, stream>>>(y2, st);
  k_bn2c<<<1, 1, 0, stream>>>(W2, b2, g2, be2, st);
  k_out<<<NB, 256, 0, stream>>>(y2, st, Wc, bc, out);
}